// Round 1
// baseline (5525.323 us; speedup 1.0000x reference)
//
#include <hip/hip_runtime.h>

#define D 128
#define FILLV 0.5f

// ---------------------------------------------------------------------------
// deg_s[i] += sum of w over edges with row==i ; deg_t over col==i
__global__ void deg_kernel(const int* __restrict__ row, const int* __restrict__ col,
                           const float* __restrict__ w,
                           float* __restrict__ deg_s, float* __restrict__ deg_t, int E) {
    int e = blockIdx.x * blockDim.x + threadIdx.x;
    if (e >= E) return;
    float we = w[e];
    atomicAdd(&deg_s[row[e]], we);
    atomicAdd(&deg_t[col[e]], we);
}

// deg -> 1/(deg + FILL)   (deg+FILL >= 0.5, never zero)
__global__ void invert_kernel(float* __restrict__ deg_s, float* __restrict__ deg_t, int N) {
    int i = blockIdx.x * blockDim.x + threadIdx.x;
    if (i >= N) return;
    deg_s[i] = 1.0f / (deg_s[i] + FILLV);
    deg_t[i] = 1.0f / (deg_t[i] + FILLV);
}

// ---------------------------------------------------------------------------
// Hop-1 scatter: nxt_s[col] += (w/deg_s[row]) * cur_s[row]
//                nxt_t[row] += (w/deg_t[col]) * cur_t[col]
// 32 float4-chunks per edge; consecutive lanes cover one edge's 128 features.
__global__ void scatter1_kernel(const int* __restrict__ row, const int* __restrict__ col,
                                const float* __restrict__ w,
                                const float* __restrict__ dinv_s, const float* __restrict__ dinv_t,
                                const float* __restrict__ cur_s, const float* __restrict__ cur_t,
                                float* __restrict__ nxt_s, float* __restrict__ nxt_t, int E) {
    long long idx = (long long)blockIdx.x * blockDim.x + threadIdx.x;
    int e = (int)(idx >> 5);
    int c = (int)(idx & 31);
    if (e >= E) return;
    int r = row[e], cl = col[e];
    float we = w[e];
    float wns = we * dinv_s[r];
    float wnt = we * dinv_t[cl];
    float4 vs = ((const float4*)(cur_s + (size_t)r  * D))[c];
    float4 vt = ((const float4*)(cur_t + (size_t)cl * D))[c];
    float* ds = nxt_s + (size_t)cl * D + c * 4;
    float* dt = nxt_t + (size_t)r  * D + c * 4;
    atomicAdd(ds + 0, wns * vs.x);
    atomicAdd(ds + 1, wns * vs.y);
    atomicAdd(ds + 2, wns * vs.z);
    atomicAdd(ds + 3, wns * vs.w);
    atomicAdd(dt + 0, wnt * vt.x);
    atomicAdd(dt + 1, wnt * vt.y);
    atomicAdd(dt + 2, wnt * vt.z);
    atomicAdd(dt + 3, wnt * vt.w);
}

// Hop-1 epilogue: a += selfw * x (a becomes c1) ; out = w0*x + w1*c1 (dense write)
__global__ void epilogue1_kernel(float* __restrict__ a_s, float* __restrict__ a_t,
                                 const float* __restrict__ x_s, const float* __restrict__ x_t,
                                 const float* __restrict__ dinv_s, const float* __restrict__ dinv_t,
                                 float* __restrict__ out,
                                 const float* __restrict__ w_s, const float* __restrict__ w_t, int N) {
    int idx = blockIdx.x * blockDim.x + threadIdx.x;
    int i = idx >> 5;
    int c = idx & 31;
    if (i >= N) return;
    float ss = FILLV * dinv_s[i];
    float st = FILLV * dinv_t[i];
    float ws0 = w_s[0], ws1 = w_s[1];
    float wt0 = w_t[0], wt1 = w_t[1];
    size_t base = (size_t)i * D;
    float4 xs = ((const float4*)(x_s + base))[c];
    float4 xt = ((const float4*)(x_t + base))[c];
    float4 as = ((float4*)(a_s + base))[c];
    float4 at = ((float4*)(a_t + base))[c];
    as.x += ss * xs.x; as.y += ss * xs.y; as.z += ss * xs.z; as.w += ss * xs.w;
    at.x += st * xt.x; at.y += st * xt.y; at.z += st * xt.z; at.w += st * xt.w;
    ((float4*)(a_s + base))[c] = as;
    ((float4*)(a_t + base))[c] = at;
    size_t obase = (size_t)i * 2 * D;
    float4 os, ot;
    os.x = ws0 * xs.x + ws1 * as.x;
    os.y = ws0 * xs.y + ws1 * as.y;
    os.z = ws0 * xs.z + ws1 * as.z;
    os.w = ws0 * xs.w + ws1 * as.w;
    ot.x = wt0 * xt.x + wt1 * at.x;
    ot.y = wt0 * xt.y + wt1 * at.y;
    ot.z = wt0 * xt.z + wt1 * at.z;
    ot.w = wt0 * xt.w + wt1 * at.w;
    ((float4*)(out + obase))[c]     = os;
    ((float4*)(out + obase + D))[c] = ot;
}

// Hop-2 scatter: accumulate w2 * conv(c1) straight into the output halves.
__global__ void scatter2_kernel(const int* __restrict__ row, const int* __restrict__ col,
                                const float* __restrict__ w,
                                const float* __restrict__ dinv_s, const float* __restrict__ dinv_t,
                                const float* __restrict__ a_s, const float* __restrict__ a_t,
                                float* __restrict__ out,
                                const float* __restrict__ w_s, const float* __restrict__ w_t, int E) {
    long long idx = (long long)blockIdx.x * blockDim.x + threadIdx.x;
    int e = (int)(idx >> 5);
    int c = (int)(idx & 31);
    if (e >= E) return;
    int r = row[e], cl = col[e];
    float we = w[e];
    float wns = we * dinv_s[r]  * w_s[2];
    float wnt = we * dinv_t[cl] * w_t[2];
    float4 vs = ((const float4*)(a_s + (size_t)r  * D))[c];
    float4 vt = ((const float4*)(a_t + (size_t)cl * D))[c];
    float* ds = out + (size_t)cl * 2 * D + c * 4;      // feat_s half
    float* dt = out + (size_t)r  * 2 * D + D + c * 4;  // feat_t half
    atomicAdd(ds + 0, wns * vs.x);
    atomicAdd(ds + 1, wns * vs.y);
    atomicAdd(ds + 2, wns * vs.z);
    atomicAdd(ds + 3, wns * vs.w);
    atomicAdd(dt + 0, wnt * vt.x);
    atomicAdd(dt + 1, wnt * vt.y);
    atomicAdd(dt + 2, wnt * vt.z);
    atomicAdd(dt + 3, wnt * vt.w);
}

// Hop-2 epilogue: out += w2 * selfw * c1   (plain RMW, scatter2 already done)
__global__ void epilogue2_kernel(const float* __restrict__ a_s, const float* __restrict__ a_t,
                                 const float* __restrict__ dinv_s, const float* __restrict__ dinv_t,
                                 float* __restrict__ out,
                                 const float* __restrict__ w_s, const float* __restrict__ w_t, int N) {
    int idx = blockIdx.x * blockDim.x + threadIdx.x;
    int i = idx >> 5;
    int c = idx & 31;
    if (i >= N) return;
    float ss = FILLV * dinv_s[i] * w_s[2];
    float st = FILLV * dinv_t[i] * w_t[2];
    size_t base = (size_t)i * D;
    float4 as = ((const float4*)(a_s + base))[c];
    float4 at = ((const float4*)(a_t + base))[c];
    size_t obase = (size_t)i * 2 * D;
    float4 os = ((float4*)(out + obase))[c];
    float4 ot = ((float4*)(out + obase + D))[c];
    os.x += ss * as.x; os.y += ss * as.y; os.z += ss * as.z; os.w += ss * as.w;
    ot.x += st * at.x; ot.y += st * at.y; ot.z += st * at.z; ot.w += st * at.w;
    ((float4*)(out + obase))[c]     = os;
    ((float4*)(out + obase + D))[c] = ot;
}

// ---------------------------------------------------------------------------
extern "C" void kernel_launch(void* const* d_in, const int* in_sizes, int n_in,
                              void* d_out, int out_size, void* d_ws, size_t ws_size,
                              hipStream_t stream) {
    const float* x_s = (const float*)d_in[0];
    const float* x_t = (const float*)d_in[1];
    const int*   ei  = (const int*)d_in[2];
    const float* ew  = (const float*)d_in[3];
    const float* w_s = (const float*)d_in[4];
    const float* w_t = (const float*)d_in[5];
    const int N = in_sizes[0] / D;
    const int E = in_sizes[3];
    const int* row = ei;
    const int* col = ei + E;

    float* ws_f    = (float*)d_ws;
    float* dinv_s  = ws_f;                       // N
    float* dinv_t  = dinv_s + N;                 // N
    float* a_s     = dinv_t + N;                 // N*D
    float* a_t     = a_s + (size_t)N * D;        // N*D
    float* out     = (float*)d_out;

    // zero: dinv_s, dinv_t, a_s, a_t are contiguous
    size_t zero_bytes = ((size_t)2 * N + (size_t)2 * N * D) * sizeof(float);
    hipMemsetAsync(d_ws, 0, zero_bytes, stream);

    deg_kernel<<<(E + 255) / 256, 256, 0, stream>>>(row, col, ew, dinv_s, dinv_t, E);
    invert_kernel<<<(N + 255) / 256, 256, 0, stream>>>(dinv_s, dinv_t, N);

    long long work_e = (long long)E * 32;
    long long work_n = (long long)N * 32;
    int blk_e = (int)((work_e + 255) / 256);
    int blk_n = (int)((work_n + 255) / 256);

    scatter1_kernel<<<blk_e, 256, 0, stream>>>(row, col, ew, dinv_s, dinv_t,
                                               x_s, x_t, a_s, a_t, E);
    epilogue1_kernel<<<blk_n, 256, 0, stream>>>(a_s, a_t, x_s, x_t, dinv_s, dinv_t,
                                                out, w_s, w_t, N);
    scatter2_kernel<<<blk_e, 256, 0, stream>>>(row, col, ew, dinv_s, dinv_t,
                                               a_s, a_t, out, w_s, w_t, E);
    epilogue2_kernel<<<blk_n, 256, 0, stream>>>(a_s, a_t, dinv_s, dinv_t,
                                                out, w_s, w_t, N);
}

// Round 2
// 809.287 us; speedup vs baseline: 6.8274x; 6.8274x over previous
//
#include <hip/hip_runtime.h>

#define D 128
#define FILLV 0.5f

// ---------------------------------------------------------------------------
// Pass 1: weighted degrees (for normalization) + bucket counts (for CSR).
//   deg_s over row (s-side normalizer), deg_t over col (t-side normalizer)
//   cnt_s over col (s-side pull buckets), cnt_t over row (t-side pull buckets)
__global__ void deg_cnt_kernel(const int* __restrict__ row, const int* __restrict__ col,
                               const float* __restrict__ w,
                               float* __restrict__ deg_s, float* __restrict__ deg_t,
                               int* __restrict__ cnt_s, int* __restrict__ cnt_t, int E) {
    int e = blockIdx.x * blockDim.x + threadIdx.x;
    if (e >= E) return;
    int r = row[e], c = col[e];
    float we = w[e];
    atomicAdd(&deg_s[r], we);
    atomicAdd(&deg_t[c], we);
    atomicAdd(&cnt_s[c], 1);
    atomicAdd(&cnt_t[r], 1);
}

// deg -> 1/(deg + FILL)   (deg+FILL >= FILL > 0, never zero)
__global__ void invert_kernel(float* __restrict__ deg_s, float* __restrict__ deg_t, int N) {
    int i = blockIdx.x * blockDim.x + threadIdx.x;
    if (i >= N) return;
    deg_s[i] = 1.0f / (deg_s[i] + FILLV);
    deg_t[i] = 1.0f / (deg_t[i] + FILLV);
}

// Single-block exclusive scan of cnt[N] -> start[N+1]; also copies to cur[N].
// 1024 threads, each owns a contiguous chunk; Hillis-Steele across chunk sums.
__global__ void scan_kernel(const int* __restrict__ cnt, int* __restrict__ start,
                            int* __restrict__ cur, int N) {
    __shared__ int sums[1024];
    int t = threadIdx.x;
    int C = (N + 1023) / 1024;
    int lo = t * C;
    int hi = min(lo + C, N);
    int s = 0;
    for (int i = lo; i < hi; i++) s += cnt[i];
    sums[t] = s;
    __syncthreads();
    for (int off = 1; off < 1024; off <<= 1) {
        int v = 0;
        if (t >= off) v = sums[t - off];
        __syncthreads();
        if (t >= off) sums[t] += v;
        __syncthreads();
    }
    int run = (t == 0) ? 0 : sums[t - 1];
    for (int i = lo; i < hi; i++) {
        start[i] = run;
        cur[i] = run;
        run += cnt[i];
    }
    if (lo < N && hi == N) start[N] = run;
}

// Pass 2: scatter edges into CSR buckets. Payload packs (src_idx, w*dinv[src])
// into one int2 so the pull loop does a single 8B load per edge.
__global__ void fill_kernel(const int* __restrict__ row, const int* __restrict__ col,
                            const float* __restrict__ w,
                            const float* __restrict__ dinv_s, const float* __restrict__ dinv_t,
                            int* __restrict__ cur_s, int* __restrict__ cur_t,
                            int2* __restrict__ edge_s, int2* __restrict__ edge_t, int E) {
    int e = blockIdx.x * blockDim.x + threadIdx.x;
    if (e >= E) return;
    int r = row[e], c = col[e];
    float we = w[e];
    int ps = atomicAdd(&cur_s[c], 1);
    edge_s[ps] = make_int2(r, __float_as_int(we * dinv_s[r]));
    int pt = atomicAdd(&cur_t[r], 1);
    edge_t[pt] = make_int2(c, __float_as_int(we * dinv_t[c]));
}

// ---------------------------------------------------------------------------
// Hop-1 pull: one wave per node, lane handles features [2l, 2l+1].
//   a[i] = sum_{e in bucket(i)} wn_e * x[idx_e] + FILL*dinv[i]*x[i]
__global__ void pull1_kernel(const int* __restrict__ start, const int2* __restrict__ edge,
                             const float* __restrict__ dinv, const float* __restrict__ x,
                             float* __restrict__ a, int N) {
    int wid = (int)(((long long)blockIdx.x * blockDim.x + threadIdx.x) >> 6);
    int lane = threadIdx.x & 63;
    if (wid >= N) return;
    int s0 = start[wid], s1 = start[wid + 1];
    float accx = 0.f, accy = 0.f;
    for (int base = s0; base < s1; base += 64) {
        int m = min(64, s1 - base);
        int myi = 0;
        float myw = 0.f;
        if (lane < m) {
            int2 p = edge[base + lane];
            myi = p.x;
            myw = __int_as_float(p.y);
        }
        for (int k = 0; k < m; k++) {
            int idx = __shfl(myi, k);
            float wv = __shfl(myw, k);
            float2 v = *(const float2*)(x + (size_t)idx * D + lane * 2);
            accx += wv * v.x;
            accy += wv * v.y;
        }
    }
    float sw = FILLV * dinv[wid];
    float2 xv = *(const float2*)(x + (size_t)wid * D + lane * 2);
    accx += sw * xv.x;
    accy += sw * xv.y;
    float2 o = make_float2(accx, accy);
    *(float2*)(a + (size_t)wid * D + lane * 2) = o;
}

// Hop-2 pull + fused epilogue:
//   c2 = sum wn_e * a[idx_e] + FILL*dinv[i]*a[i]
//   out_half[i] = w0*x[i] + w1*a[i] + w2*c2
__global__ void pull2_kernel(const int* __restrict__ start, const int2* __restrict__ edge,
                             const float* __restrict__ dinv, const float* __restrict__ x,
                             const float* __restrict__ a, float* __restrict__ out_half,
                             const float* __restrict__ wv3, int N) {
    int wid = (int)(((long long)blockIdx.x * blockDim.x + threadIdx.x) >> 6);
    int lane = threadIdx.x & 63;
    if (wid >= N) return;
    int s0 = start[wid], s1 = start[wid + 1];
    float accx = 0.f, accy = 0.f;
    for (int base = s0; base < s1; base += 64) {
        int m = min(64, s1 - base);
        int myi = 0;
        float myw = 0.f;
        if (lane < m) {
            int2 p = edge[base + lane];
            myi = p.x;
            myw = __int_as_float(p.y);
        }
        for (int k = 0; k < m; k++) {
            int idx = __shfl(myi, k);
            float wvk = __shfl(myw, k);
            float2 v = *(const float2*)(a + (size_t)idx * D + lane * 2);
            accx += wvk * v.x;
            accy += wvk * v.y;
        }
    }
    float sw = FILLV * dinv[wid];
    float2 av = *(const float2*)(a + (size_t)wid * D + lane * 2);
    accx += sw * av.x;
    accy += sw * av.y;
    float w0 = wv3[0], w1 = wv3[1], w2 = wv3[2];
    float2 xv = *(const float2*)(x + (size_t)wid * D + lane * 2);
    float2 o;
    o.x = w0 * xv.x + w1 * av.x + w2 * accx;
    o.y = w0 * xv.y + w1 * av.y + w2 * accy;
    *(float2*)(out_half + (size_t)wid * 2 * D + lane * 2) = o;
}

// ---------------------------------------------------------------------------
extern "C" void kernel_launch(void* const* d_in, const int* in_sizes, int n_in,
                              void* d_out, int out_size, void* d_ws, size_t ws_size,
                              hipStream_t stream) {
    const float* x_s = (const float*)d_in[0];
    const float* x_t = (const float*)d_in[1];
    const int*   ei  = (const int*)d_in[2];
    const float* ew  = (const float*)d_in[3];
    const float* w_s = (const float*)d_in[4];
    const float* w_t = (const float*)d_in[5];
    const int N = in_sizes[0] / D;
    const int E = in_sizes[3];
    const int* row = ei;
    const int* col = ei + E;

    // Workspace layout (ints/floats are both 4B):
    // [deg_s N][deg_t N][cnt_s N][cnt_t N]  <- memset region (4N)
    // [start_s N+1][start_t N+1][cur_s N][cur_t N]
    // [edge_s 2E][edge_t 2E]   (int2-packed: idx + wn)
    // [a_s N*D][a_t N*D]
    float* f      = (float*)d_ws;
    float* deg_s  = f;                    // becomes dinv_s after invert
    float* deg_t  = f + N;                // becomes dinv_t
    int*   cnt_s  = (int*)(f + 2 * (size_t)N);
    int*   cnt_t  = cnt_s + N;
    int*   start_s = cnt_t + N;
    int*   start_t = start_s + (N + 1);
    int*   cur_s  = start_t + (N + 1);
    int*   cur_t  = cur_s + N;
    int2*  edge_s = (int2*)(cur_t + N);        // offset 8N+2 ints: 8B-aligned for N even
    int2*  edge_t = edge_s + E;
    float* a_s    = (float*)(edge_t + E);
    float* a_t    = a_s + (size_t)N * D;
    float* out    = (float*)d_out;

    hipMemsetAsync(d_ws, 0, (size_t)4 * N * sizeof(int), stream);

    int blkE = (E + 255) / 256;
    int blkN = (N + 255) / 256;
    deg_cnt_kernel<<<blkE, 256, 0, stream>>>(row, col, ew, deg_s, deg_t, cnt_s, cnt_t, E);
    invert_kernel<<<blkN, 256, 0, stream>>>(deg_s, deg_t, N);
    scan_kernel<<<1, 1024, 0, stream>>>(cnt_s, start_s, cur_s, N);
    scan_kernel<<<1, 1024, 0, stream>>>(cnt_t, start_t, cur_t, N);
    fill_kernel<<<blkE, 256, 0, stream>>>(row, col, ew, deg_s, deg_t,
                                          cur_s, cur_t, edge_s, edge_t, E);

    long long waves = (long long)N * 64;
    int blkW = (int)((waves + 255) / 256);
    pull1_kernel<<<blkW, 256, 0, stream>>>(start_s, edge_s, deg_s, x_s, a_s, N);
    pull1_kernel<<<blkW, 256, 0, stream>>>(start_t, edge_t, deg_t, x_t, a_t, N);
    pull2_kernel<<<blkW, 256, 0, stream>>>(start_s, edge_s, deg_s, x_s, a_s, out,     w_s, N);
    pull2_kernel<<<blkW, 256, 0, stream>>>(start_t, edge_t, deg_t, x_t, a_t, out + D, w_t, N);
}

// Round 3
// 743.940 us; speedup vs baseline: 7.4271x; 1.0878x over previous
//
#include <hip/hip_runtime.h>

#define D 128
#define FILLV 0.5f
#define PAD 16   // counters strided to 64B: atomics to different nodes never share a line

// ---------------------------------------------------------------------------
// Pass 1: bucket counts only (padded). cnt_s over col, cnt_t over row.
__global__ void cnt_kernel(const int* __restrict__ row, const int* __restrict__ col,
                           int* __restrict__ cnt_s, int* __restrict__ cnt_t, int E) {
    int e = blockIdx.x * blockDim.x + threadIdx.x;
    if (e >= E) return;
    atomicAdd(&cnt_s[col[e] * PAD], 1);
    atomicAdd(&cnt_t[row[e] * PAD], 1);
}

// Exclusive scan of padded cnt -> compact start[N+1]; writes running offset back
// into cnt (which then serves as the fill cursor). grid=2: block 0 = s, 1 = t.
__global__ void scan_kernel(int* __restrict__ cnt_s, int* __restrict__ cnt_t,
                            int* __restrict__ start_s, int* __restrict__ start_t, int N) {
    int* cnt   = (blockIdx.x == 0) ? cnt_s : cnt_t;
    int* start = (blockIdx.x == 0) ? start_s : start_t;
    __shared__ int sums[1024];
    int t = threadIdx.x;
    int C = (N + 1023) / 1024;
    int lo = t * C;
    int hi = min(lo + C, N);
    int s = 0;
    for (int i = lo; i < hi; i++) s += cnt[i * PAD];
    sums[t] = s;
    __syncthreads();
    for (int off = 1; off < 1024; off <<= 1) {
        int v = 0;
        if (t >= off) v = sums[t - off];
        __syncthreads();
        if (t >= off) sums[t] += v;
        __syncthreads();
    }
    int run = (t == 0) ? 0 : sums[t - 1];
    for (int i = lo; i < hi; i++) {
        int c = cnt[i * PAD];
        start[i] = run;
        cnt[i * PAD] = run;   // becomes cursor for fill
        run += c;
    }
    if (lo < N && hi == N) start[N] = run;
}

// Pass 2: scatter edges into buckets; payload = (neighbor idx, RAW weight).
__global__ void fill_kernel(const int* __restrict__ row, const int* __restrict__ col,
                            const float* __restrict__ w,
                            int* __restrict__ cur_s, int* __restrict__ cur_t,
                            int2* __restrict__ edge_s, int2* __restrict__ edge_t, int E) {
    int e = blockIdx.x * blockDim.x + threadIdx.x;
    if (e >= E) return;
    int r = row[e], c = col[e];
    int wbits = __float_as_int(w[e]);
    int ps = atomicAdd(&cur_s[c * PAD], 1);
    edge_s[ps] = make_int2(r, wbits);
    int pt = atomicAdd(&cur_t[r * PAD], 1);
    edge_t[pt] = make_int2(c, wbits);
}

// Degrees from CSR segments (no atomics):
//   deg_s[i] = sum w over row==i  == weight-sum of edge_t bucket i
//   deg_t[i] = sum w over col==i  == weight-sum of edge_s bucket i
__global__ void deg_kernel(const int* __restrict__ start_s, const int* __restrict__ start_t,
                           const int2* __restrict__ edge_s, const int2* __restrict__ edge_t,
                           float* __restrict__ dinv_s, float* __restrict__ dinv_t, int N) {
    int i = blockIdx.x * blockDim.x + threadIdx.x;
    if (i >= 2 * N) return;
    if (i < N) {
        int s0 = start_t[i], s1 = start_t[i + 1];
        float s = 0.f;
        for (int k = s0; k < s1; k++) s += __int_as_float(edge_t[k].y);
        dinv_s[i] = 1.0f / (s + FILLV);
    } else {
        int j = i - N;
        int s0 = start_s[j], s1 = start_s[j + 1];
        float s = 0.f;
        for (int k = s0; k < s1; k++) s += __int_as_float(edge_s[k].y);
        dinv_t[j] = 1.0f / (s + FILLV);
    }
}

// Fold dinv of the gathered endpoint into each packed edge weight.
__global__ void scale_kernel(int2* __restrict__ edge_s, int2* __restrict__ edge_t,
                             const float* __restrict__ dinv_s, const float* __restrict__ dinv_t,
                             int E) {
    int j = blockIdx.x * blockDim.x + threadIdx.x;
    if (j >= 2 * E) return;
    if (j < E) {
        int2 p = edge_s[j];
        edge_s[j] = make_int2(p.x, __float_as_int(__int_as_float(p.y) * dinv_s[p.x]));
    } else {
        int2 p = edge_t[j - E];
        edge_t[j - E] = make_int2(p.x, __float_as_int(__int_as_float(p.y) * dinv_t[p.x]));
    }
}

// ---------------------------------------------------------------------------
// Hop-1 pull, both sides in one grid. Wave per node; wid forced wave-uniform so
// edge/start loads scalarize (s_load); lane covers features [2l, 2l+1].
__global__ void pull1_kernel(const int* __restrict__ start_s, const int* __restrict__ start_t,
                             const int2* __restrict__ edge_s, const int2* __restrict__ edge_t,
                             const float* __restrict__ dinv_s, const float* __restrict__ dinv_t,
                             const float* __restrict__ x_s, const float* __restrict__ x_t,
                             float* __restrict__ a_s, float* __restrict__ a_t, int N) {
    int wid0 = (int)(((long long)blockIdx.x * blockDim.x + threadIdx.x) >> 6);
    int wid = __builtin_amdgcn_readfirstlane(wid0);
    int lane = threadIdx.x & 63;
    if (wid >= 2 * N) return;
    const int* start; const int2* edge; const float* dinv; const float* x; float* a; int i;
    if (wid < N) { i = wid;     start = start_s; edge = edge_s; dinv = dinv_s; x = x_s; a = a_s; }
    else         { i = wid - N; start = start_t; edge = edge_t; dinv = dinv_t; x = x_t; a = a_t; }
    int s0 = start[i], s1 = start[i + 1];
    float ax = 0.f, ay = 0.f;
    for (int k = s0; k < s1; k++) {
        int2 p = edge[k];
        float wv = __int_as_float(p.y);
        float2 v = *(const float2*)(x + (size_t)p.x * D + lane * 2);
        ax += wv * v.x;
        ay += wv * v.y;
    }
    float sw = FILLV * dinv[i];
    float2 xv = *(const float2*)(x + (size_t)i * D + lane * 2);
    ax += sw * xv.x;
    ay += sw * xv.y;
    *(float2*)(a + (size_t)i * D + lane * 2) = make_float2(ax, ay);
}

// Hop-2 pull + fused epilogue, both sides:
//   out_half[i] = w0*x[i] + w1*a[i] + w2*(sum wn*a[nb] + FILL*dinv[i]*a[i])
__global__ void pull2_kernel(const int* __restrict__ start_s, const int* __restrict__ start_t,
                             const int2* __restrict__ edge_s, const int2* __restrict__ edge_t,
                             const float* __restrict__ dinv_s, const float* __restrict__ dinv_t,
                             const float* __restrict__ x_s, const float* __restrict__ x_t,
                             const float* __restrict__ a_s, const float* __restrict__ a_t,
                             float* __restrict__ out,
                             const float* __restrict__ w_s, const float* __restrict__ w_t, int N) {
    int wid0 = (int)(((long long)blockIdx.x * blockDim.x + threadIdx.x) >> 6);
    int wid = __builtin_amdgcn_readfirstlane(wid0);
    int lane = threadIdx.x & 63;
    if (wid >= 2 * N) return;
    const int* start; const int2* edge; const float* dinv;
    const float* x; const float* a; const float* wv3; int i, half;
    if (wid < N) { i = wid;     start = start_s; edge = edge_s; dinv = dinv_s;
                   x = x_s; a = a_s; wv3 = w_s; half = 0; }
    else         { i = wid - N; start = start_t; edge = edge_t; dinv = dinv_t;
                   x = x_t; a = a_t; wv3 = w_t; half = D; }
    int s0 = start[i], s1 = start[i + 1];
    float ax = 0.f, ay = 0.f;
    for (int k = s0; k < s1; k++) {
        int2 p = edge[k];
        float wv = __int_as_float(p.y);
        float2 v = *(const float2*)(a + (size_t)p.x * D + lane * 2);
        ax += wv * v.x;
        ay += wv * v.y;
    }
    float sw = FILLV * dinv[i];
    float2 av = *(const float2*)(a + (size_t)i * D + lane * 2);
    ax += sw * av.x;
    ay += sw * av.y;
    float w0 = wv3[0], w1 = wv3[1], w2 = wv3[2];
    float2 xv = *(const float2*)(x + (size_t)i * D + lane * 2);
    float2 o;
    o.x = w0 * xv.x + w1 * av.x + w2 * ax;
    o.y = w0 * xv.y + w1 * av.y + w2 * ay;
    *(float2*)(out + (size_t)i * 2 * D + half + lane * 2) = o;
}

// ---------------------------------------------------------------------------
extern "C" void kernel_launch(void* const* d_in, const int* in_sizes, int n_in,
                              void* d_out, int out_size, void* d_ws, size_t ws_size,
                              hipStream_t stream) {
    const float* x_s = (const float*)d_in[0];
    const float* x_t = (const float*)d_in[1];
    const int*   ei  = (const int*)d_in[2];
    const float* ew  = (const float*)d_in[3];
    const float* w_s = (const float*)d_in[4];
    const float* w_t = (const float*)d_in[5];
    const int N = in_sizes[0] / D;
    const int E = in_sizes[3];
    const int* row = ei;
    const int* col = ei + E;

    // Workspace (4B units):
    // [dinv_s N][dinv_t N][start_s N+1][start_t N+1][edge_s 2E][edge_t 2E][a_s ND][a_t ND]
    // Padded cnt/cursor arrays (2*N*PAD ints) ALIAS the a_s region: cnt dies at
    // fill_kernel, a_s is born at pull1_kernel — lifetimes don't overlap.
    float* f       = (float*)d_ws;
    float* dinv_s  = f;
    float* dinv_t  = f + N;
    int*   start_s = (int*)(f + 2 * (size_t)N);
    int*   start_t = start_s + (N + 1);
    int2*  edge_s  = (int2*)(start_t + (N + 1));
    int2*  edge_t  = edge_s + E;
    float* a_s     = (float*)(edge_t + E);
    float* a_t     = a_s + (size_t)N * D;
    int*   cnt_s   = (int*)a_s;             // alias, dead before pull1
    int*   cnt_t   = cnt_s + (size_t)N * PAD;
    float* out     = (float*)d_out;

    hipMemsetAsync(cnt_s, 0, (size_t)2 * N * PAD * sizeof(int), stream);

    int blkE  = (E + 255) / 256;
    int blk2N = (2 * N + 255) / 256;
    int blk2E = (2 * E + 255) / 256;
    cnt_kernel<<<blkE, 256, 0, stream>>>(row, col, cnt_s, cnt_t, E);
    scan_kernel<<<2, 1024, 0, stream>>>(cnt_s, cnt_t, start_s, start_t, N);
    fill_kernel<<<blkE, 256, 0, stream>>>(row, col, ew, cnt_s, cnt_t, edge_s, edge_t, E);
    deg_kernel<<<blk2N, 256, 0, stream>>>(start_s, start_t, edge_s, edge_t, dinv_s, dinv_t, N);
    scale_kernel<<<blk2E, 256, 0, stream>>>(edge_s, edge_t, dinv_s, dinv_t, E);

    long long pull_threads = (long long)2 * N * 64;
    int blkP = (int)((pull_threads + 255) / 256);
    pull1_kernel<<<blkP, 256, 0, stream>>>(start_s, start_t, edge_s, edge_t,
                                           dinv_s, dinv_t, x_s, x_t, a_s, a_t, N);
    pull2_kernel<<<blkP, 256, 0, stream>>>(start_s, start_t, edge_s, edge_t,
                                           dinv_s, dinv_t, x_s, x_t, a_s, a_t,
                                           out, w_s, w_t, N);
}

// Round 5
// 618.952 us; speedup vs baseline: 8.9269x; 1.2019x over previous
//
#include <hip/hip_runtime.h>

#define D 128
#define FILLV 0.5f
#define PAD 16   // counters strided to 64B lines

// ---------------------------------------------------------------------------
// Pass 1: counts + weighted degrees, fused. Combined padded array cntp[2N]:
//   line j (j<N):  [cnt_s(col=j), deg_t(col=j)]   -- both keyed by col
//   line N+r:      [cnt_t(row=r), deg_s(row=r)]   -- both keyed by row
// Each edge touches exactly 2 lines with an int+float atomic each.
__global__ void cnt_deg_kernel(const int* __restrict__ row, const int* __restrict__ col,
                               const float* __restrict__ w,
                               int* __restrict__ cntp, int E, int N) {
    int e = blockIdx.x * blockDim.x + threadIdx.x;
    if (e >= E) return;
    int r = row[e], c = col[e];
    float we = w[e];
    atomicAdd(&cntp[(size_t)c * PAD], 1);
    atomicAdd((float*)&cntp[(size_t)c * PAD + 1], we);
    atomicAdd(&cntp[((size_t)N + r) * PAD], 1);
    atomicAdd((float*)&cntp[((size_t)N + r) * PAD + 1], we);
}

// dinv from padded degrees (deg+FILL >= FILL, never zero).
__global__ void invert_kernel(const int* __restrict__ cntp,
                              float* __restrict__ dinv_s, float* __restrict__ dinv_t, int N) {
    int i = blockIdx.x * blockDim.x + threadIdx.x;
    if (i >= 2 * N) return;
    float dv = __int_as_float(cntp[(size_t)i * PAD + 1]);
    float inv = 1.0f / (dv + FILLV);
    if (i < N) dinv_t[i] = inv;        // lines [0,N) hold deg_t (by col)
    else       dinv_s[i - N] = inv;    // lines [N,2N) hold deg_s (by row)
}

// --------------------------- 3-phase parallel scan --------------------------
// Phase A: per-256-tile sums of the padded counters.
__global__ void scanA_kernel(const int* __restrict__ cntp, int* __restrict__ tsum, int total) {
    __shared__ int sh[256];
    int gid = blockIdx.x * 256 + threadIdx.x;
    sh[threadIdx.x] = (gid < total) ? cntp[(size_t)gid * PAD] : 0;
    __syncthreads();
    for (int off = 128; off > 0; off >>= 1) {
        if (threadIdx.x < off) sh[threadIdx.x] += sh[threadIdx.x + off];
        __syncthreads();
    }
    if (threadIdx.x == 0) tsum[blockIdx.x] = sh[0];
}

// Phase B: one block, exclusive scan of tile sums (nt <= 512).
__global__ void scanB_kernel(const int* __restrict__ tsum, int* __restrict__ toff, int nt) {
    __shared__ int sh[512];
    int t = threadIdx.x;
    int v = (t < nt) ? tsum[t] : 0;
    sh[t] = v;
    __syncthreads();
    for (int off = 1; off < 512; off <<= 1) {
        int u = 0;
        if (t >= off) u = sh[t - off];
        __syncthreads();
        sh[t] += u;
        __syncthreads();
    }
    if (t < nt) toff[t] = sh[t] - v;
}

// Phase C: per-tile exclusive scan + tile offset; writes compact start[] and
// seeds the fill cursor back into the padded slot.
__global__ void scanC_kernel(int* __restrict__ cntp, const int* __restrict__ toff,
                             int* __restrict__ start, int total, int grand_total) {
    __shared__ int sh[256];
    int gid = blockIdx.x * 256 + threadIdx.x;
    int v = (gid < total) ? cntp[(size_t)gid * PAD] : 0;
    sh[threadIdx.x] = v;
    __syncthreads();
    for (int off = 1; off < 256; off <<= 1) {
        int u = 0;
        if (threadIdx.x >= off) u = sh[threadIdx.x - off];
        __syncthreads();
        sh[threadIdx.x] += u;
        __syncthreads();
    }
    int run = toff[blockIdx.x] + sh[threadIdx.x] - v;   // exclusive
    if (gid < total) {
        start[gid] = run;
        cntp[(size_t)gid * PAD] = run;
    }
    if (gid == 0) start[total] = grand_total;
}

// Pass 2: scatter edges into the shared pool; weight folded with dinv[src].
__global__ void fill_kernel(const int* __restrict__ row, const int* __restrict__ col,
                            const float* __restrict__ w,
                            const float* __restrict__ dinv_s, const float* __restrict__ dinv_t,
                            int* __restrict__ cntp, int2* __restrict__ edges, int E, int N) {
    int e = blockIdx.x * blockDim.x + threadIdx.x;
    if (e >= E) return;
    int r = row[e], c = col[e];
    float we = w[e];
    int ps = atomicAdd(&cntp[(size_t)c * PAD], 1);
    edges[ps] = make_int2(r, __float_as_int(we * dinv_s[r]));
    int pt = atomicAdd(&cntp[((size_t)N + r) * PAD], 1);
    edges[pt] = make_int2(c, __float_as_int(we * dinv_t[c]));
}

// ---------------------------------------------------------------------------
// Hop-1 pull, both sides in one grid (wave wid<N = s-node wid, else t-node).
__global__ void pull1_kernel(const int* __restrict__ start, const int2* __restrict__ edges,
                             const float* __restrict__ dinv_s, const float* __restrict__ dinv_t,
                             const float* __restrict__ x_s, const float* __restrict__ x_t,
                             float* __restrict__ a_s, float* __restrict__ a_t, int N) {
    int wid0 = (int)(((long long)blockIdx.x * blockDim.x + threadIdx.x) >> 6);
    int wid = __builtin_amdgcn_readfirstlane(wid0);
    int lane = threadIdx.x & 63;
    if (wid >= 2 * N) return;
    const float* x; float* a; const float* dinv; int i;
    if (wid < N) { i = wid;     x = x_s; a = a_s; dinv = dinv_s; }
    else         { i = wid - N; x = x_t; a = a_t; dinv = dinv_t; }
    int s0 = start[wid], s1 = start[wid + 1];
    float ax = 0.f, ay = 0.f;
    for (int k = s0; k < s1; k++) {
        int2 p = edges[k];
        float wv = __int_as_float(p.y);
        float2 v = *(const float2*)(x + (size_t)p.x * D + lane * 2);
        ax += wv * v.x;
        ay += wv * v.y;
    }
    float sw = FILLV * dinv[i];
    float2 xv = *(const float2*)(x + (size_t)i * D + lane * 2);
    ax += sw * xv.x;
    ay += sw * xv.y;
    *(float2*)(a + (size_t)i * D + lane * 2) = make_float2(ax, ay);
}

// Hop-2 pull + fused epilogue:
//   out_half[i] = w0*x[i] + w1*a[i] + w2*(sum wn*a[nb] + FILL*dinv[i]*a[i])
__global__ void pull2_kernel(const int* __restrict__ start, const int2* __restrict__ edges,
                             const float* __restrict__ dinv_s, const float* __restrict__ dinv_t,
                             const float* __restrict__ x_s, const float* __restrict__ x_t,
                             const float* __restrict__ a_s, const float* __restrict__ a_t,
                             float* __restrict__ out,
                             const float* __restrict__ w_s, const float* __restrict__ w_t, int N) {
    int wid0 = (int)(((long long)blockIdx.x * blockDim.x + threadIdx.x) >> 6);
    int wid = __builtin_amdgcn_readfirstlane(wid0);
    int lane = threadIdx.x & 63;
    if (wid >= 2 * N) return;
    const float* x; const float* a; const float* dinv; const float* wv3; int i, half;
    if (wid < N) { i = wid;     x = x_s; a = a_s; dinv = dinv_s; wv3 = w_s; half = 0; }
    else         { i = wid - N; x = x_t; a = a_t; dinv = dinv_t; wv3 = w_t; half = D; }
    int s0 = start[wid], s1 = start[wid + 1];
    float ax = 0.f, ay = 0.f;
    for (int k = s0; k < s1; k++) {
        int2 p = edges[k];
        float wv = __int_as_float(p.y);
        float2 v = *(const float2*)(a + (size_t)p.x * D + lane * 2);
        ax += wv * v.x;
        ay += wv * v.y;
    }
    float sw = FILLV * dinv[i];
    float2 av = *(const float2*)(a + (size_t)i * D + lane * 2);
    ax += sw * av.x;
    ay += sw * av.y;
    float w0 = wv3[0], w1 = wv3[1], w2 = wv3[2];
    float2 xv = *(const float2*)(x + (size_t)i * D + lane * 2);
    float2 o;
    o.x = w0 * xv.x + w1 * av.x + w2 * ax;
    o.y = w0 * xv.y + w1 * av.y + w2 * ay;
    *(float2*)(out + (size_t)i * 2 * D + half + lane * 2) = o;
}

// ---------------------------------------------------------------------------
extern "C" void kernel_launch(void* const* d_in, const int* in_sizes, int n_in,
                              void* d_out, int out_size, void* d_ws, size_t ws_size,
                              hipStream_t stream) {
    const float* x_s = (const float*)d_in[0];
    const float* x_t = (const float*)d_in[1];
    const int*   ei  = (const int*)d_in[2];
    const float* ew  = (const float*)d_in[3];
    const float* w_s = (const float*)d_in[4];
    const float* w_t = (const float*)d_in[5];
    const int N = in_sizes[0] / D;
    const int E = in_sizes[3];
    const int* row = ei;
    const int* col = ei + E;

    const int total = 2 * N;                       // combined bucket count
    const int nTiles = (total + 255) / 256;        // <= 512 (N <= 65k)

    // Workspace (4B units):
    // [dinv_s N][dinv_t N][start 2N+2][tsum 512][toff 512][edges 2E int2][a_s ND][a_t ND]
    // Padded cntp (2N*PAD ints) aliases a_s: dead before pull1 writes a_s.
    float* f      = (float*)d_ws;
    float* dinv_s = f;
    float* dinv_t = f + N;
    int*   start  = (int*)(f + 2 * (size_t)N);     // 2N+2 (even pad keeps edges 8B-aligned)
    int*   tsum   = start + (total + 2);
    int*   toff   = tsum + 512;
    int2*  edges  = (int2*)(toff + 512);
    float* a_s    = (float*)(edges + 2 * (size_t)E);
    float* a_t    = a_s + (size_t)N * D;
    int*   cntp   = (int*)a_s;                     // alias, dead before pull1
    float* out    = (float*)d_out;

    hipMemsetAsync(cntp, 0, (size_t)total * PAD * sizeof(int), stream);

    int blkE  = (E + 255) / 256;
    int blk2N = (total + 255) / 256;
    cnt_deg_kernel<<<blkE, 256, 0, stream>>>(row, col, ew, cntp, E, N);
    invert_kernel<<<blk2N, 256, 0, stream>>>(cntp, dinv_s, dinv_t, N);
    scanA_kernel<<<nTiles, 256, 0, stream>>>(cntp, tsum, total);
    scanB_kernel<<<1, 512, 0, stream>>>(tsum, toff, nTiles);
    scanC_kernel<<<nTiles, 256, 0, stream>>>(cntp, toff, start, total, 2 * E);
    fill_kernel<<<blkE, 256, 0, stream>>>(row, col, ew, dinv_s, dinv_t, cntp, edges, E, N);

    long long pull_threads = (long long)total * 64;
    int blkP = (int)((pull_threads + 255) / 256);
    pull1_kernel<<<blkP, 256, 0, stream>>>(start, edges, dinv_s, dinv_t,
                                           x_s, x_t, a_s, a_t, N);
    pull2_kernel<<<blkP, 256, 0, stream>>>(start, edges, dinv_s, dinv_t,
                                           x_s, x_t, a_s, a_t, out, w_s, w_t, N);
}